// Round 1
// baseline (307.027 us; speedup 1.0000x reference)
//
#include <hip/hip_runtime.h>

// Fused causal attention, S=2048 B=2 H=16 D=128, sbhd layout, fp32 in/out,
// bf16 MFMA compute (16x16x32), flash-style online softmax.

#define S_LEN   2048
#define DDIM    128
#define ROWSTR  4096          // B*H*D: row stride in elements for s/t dimension
#define QBLK    64
#define KVBLK   32
#define NQT     32            // S_LEN / QBLK
#define NF_INV  0.08838834764831845f   // 1 / 11.313708498984761 (= 1/sqrt(128))

typedef __attribute__((ext_vector_type(4))) float f32x4;
typedef __attribute__((ext_vector_type(8))) short s16x8;
typedef __attribute__((ext_vector_type(4))) short s16x4;

__device__ inline short f2bf(float x) {
    union { float f; unsigned u; } v; v.f = x;
    unsigned r = v.u + 0x7fffu + ((v.u >> 16) & 1u);   // round-nearest-even
    return (short)(r >> 16);
}

__global__ __launch_bounds__(256)
void fattn_kernel(const float* __restrict__ q, const float* __restrict__ k,
                  const float* __restrict__ v, float* __restrict__ out)
{
    // K tile: [32][128] bf16, XOR-swizzled (byte ^= (row&7)<<4)  -> 8192 B
    // Vt tile: [128 d][36 kv bf16] pitch 72 B, kv-chunk XOR-swizzled -> 9216 B
    __shared__ char ldsK[KVBLK * 256];
    __shared__ char ldsVt[DDIM * 72];

    const int tid = threadIdx.x;
    const int w   = tid >> 6;        // wave 0..3
    const int l   = tid & 63;
    const int g   = l >> 4;          // lane group 0..3
    const int lr  = l & 15;

    const int bid = blockIdx.x;
    const int qt  = (NQT - 1) - (bid & (NQT - 1));   // heavy q-tiles first
    const int bh  = bid >> 5;                        // b*H + h
    const int qb  = qt * QBLK;

    const float* qbh = q + bh * DDIM;
    const float* kbh = k + bh * DDIM;
    const float* vbh = v + bh * DDIM;

    const int qrow = qb + 16 * w + lr;   // this lane's q row (output col of S^T)

    // ---- Q fragments: B-operand of S^T mfma. b[(g,j)] = Q[q=lr][d=32*kk+8g+j],
    //      pre-scaled by 1/NORM_FACTOR.
    s16x8 qf[4];
#pragma unroll
    for (int kk = 0; kk < 4; ++kk) {
        const float* qp = qbh + (size_t)qrow * ROWSTR + kk * 32 + g * 8;
        f32x4 a  = *(const f32x4*)qp;
        f32x4 b2 = *(const f32x4*)(qp + 4);
        s16x8 t;
#pragma unroll
        for (int i = 0; i < 4; ++i) {
            t[i]     = f2bf(a[i]  * NF_INV);
            t[4 + i] = f2bf(b2[i] * NF_INV);
        }
        qf[kk] = t;
    }

    f32x4 acc[8];
#pragma unroll
    for (int i = 0; i < 8; ++i) acc[i] = (f32x4){0.f, 0.f, 0.f, 0.f};
    float mrun = -INFINITY;
    float lrun = 0.0f;

    const int qmaxw  = qb + 16 * w + 15;   // wave-uniform last row this wave owns
    const int ntiles = 2 * qt + 2;         // ceil((qb+QBLK)/KVBLK)

    for (int t = 0; t < ntiles; ++t) {
        const int kv0 = t * KVBLK;

        // ---- stage K tile -> LDS bf16, swizzled
        {
            int r = tid >> 3;              // kv row 0..31
            int c = (tid & 7) * 16;        // f32 col base
            const float* gp = kbh + (size_t)(kv0 + r) * ROWSTR + c;
            f32x4 f0 = *(const f32x4*)gp;
            f32x4 f1 = *(const f32x4*)(gp + 4);
            f32x4 f2 = *(const f32x4*)(gp + 8);
            f32x4 f3 = *(const f32x4*)(gp + 12);
            s16x8 p0, p1;
#pragma unroll
            for (int i = 0; i < 4; ++i) {
                p0[i] = f2bf(f0[i]); p0[4 + i] = f2bf(f1[i]);
                p1[i] = f2bf(f2[i]); p1[4 + i] = f2bf(f3[i]);
            }
            unsigned b0 = r * 256 + c * 2;
            unsigned sw = (unsigned)(r & 7) << 4;
            *(s16x8*)(ldsK + (b0 ^ sw))        = p0;
            *(s16x8*)(ldsK + ((b0 + 16) ^ sw)) = p1;
        }
        // ---- stage V tile transposed -> Vt[d][kv], chunk-swizzled
        {
            int db4 = tid & 31;            // d block of 4
            int kc  = tid >> 5;            // kv chunk of 4 (0..7)
            const float* vp = vbh + (size_t)(kv0 + kc * 4) * ROWSTR + db4 * 4;
            f32x4 r0 = *(const f32x4*)vp;
            f32x4 r1 = *(const f32x4*)(vp + ROWSTR);
            f32x4 r2 = *(const f32x4*)(vp + 2 * ROWSTR);
            f32x4 r3 = *(const f32x4*)(vp + 3 * ROWSTR);
#pragma unroll
            for (int jj = 0; jj < 4; ++jj) {
                s16x4 wv;
                wv[0] = f2bf(r0[jj]); wv[1] = f2bf(r1[jj]);
                wv[2] = f2bf(r2[jj]); wv[3] = f2bf(r3[jj]);
                int dd = db4 * 4 + jj;
                *(s16x4*)(ldsVt + dd * 72 + ((kc ^ (dd & 7)) << 3)) = wv;
            }
        }
        __syncthreads();

        if (kv0 <= qmaxw) {   // wave-uniform causal tile skip
            // ---- S^T = K · Q^T : lane ends up with S[q=lr][kv0+16m+4g+r]
            f32x4 sa0 = (f32x4){0.f, 0.f, 0.f, 0.f};
            f32x4 sa1 = (f32x4){0.f, 0.f, 0.f, 0.f};
            unsigned sw0 = (unsigned)(lr & 7) << 4;
#pragma unroll
            for (int kk = 0; kk < 4; ++kk) {
                unsigned b0 = lr * 256 + kk * 64 + g * 16;
                s16x8 kf0 = *(const s16x8*)(ldsK + (b0 ^ sw0));
                sa0 = __builtin_amdgcn_mfma_f32_16x16x32_bf16(kf0, qf[kk], sa0, 0, 0, 0);
                unsigned b1 = (lr + 16) * 256 + kk * 64 + g * 16;
                s16x8 kf1 = *(const s16x8*)(ldsK + (b1 ^ sw0));
                sa1 = __builtin_amdgcn_mfma_f32_16x16x32_bf16(kf1, qf[kk], sa1, 0, 0, 0);
            }

            // ---- online softmax (row q = lr spread over lanes {lr,lr+16,lr+32,lr+48})
            float s_[8];
#pragma unroll
            for (int r = 0; r < 4; ++r) { s_[r] = sa0[r]; s_[4 + r] = sa1[r]; }
            float mx = -INFINITY;
#pragma unroll
            for (int j = 0; j < 8; ++j) {
                int kva = kv0 + ((j >> 2) << 4) + 4 * g + (j & 3);
                if (kva > qrow) s_[j] = -INFINITY;
                mx = fmaxf(mx, s_[j]);
            }
            mx = fmaxf(mx, __shfl_xor(mx, 16));
            mx = fmaxf(mx, __shfl_xor(mx, 32));
            float mnew = fmaxf(mrun, mx);
            float corr = __expf(mrun - mnew);
            float ts = 0.f;
#pragma unroll
            for (int j = 0; j < 8; ++j) {
                float p = __expf(s_[j] - mnew);
                s_[j] = p;
                ts += p;
            }
            ts += __shfl_xor(ts, 16);
            ts += __shfl_xor(ts, 32);
            lrun = lrun * corr + ts;
            mrun = mnew;

            s16x8 pf;
#pragma unroll
            for (int j = 0; j < 8; ++j) pf[j] = f2bf(s_[j]);
#pragma unroll
            for (int db = 0; db < 8; ++db) {
#pragma unroll
                for (int r = 0; r < 4; ++r) acc[db][r] *= corr;
            }

            // ---- O^T += V^T · P^T : A-frag a[(g,j)] = V[kv0+16(j>>2)+4g+(j&3)][dd]
            int dr = lr;
#pragma unroll
            for (int db = 0; db < 8; ++db) {
                int dd = db * 16 + dr;
                const char* vb = ldsVt + dd * 72;
                s16x4 v0 = *(const s16x4*)(vb + ((g       ^ (dd & 7)) << 3));
                s16x4 v1 = *(const s16x4*)(vb + (((g + 4) ^ (dd & 7)) << 3));
                s16x8 vf;
#pragma unroll
                for (int i = 0; i < 4; ++i) { vf[i] = v0[i]; vf[4 + i] = v1[i]; }
                acc[db] = __builtin_amdgcn_mfma_f32_16x16x32_bf16(vf, pf, acc[db], 0, 0, 0);
            }
        }
        __syncthreads();
    }

    // ---- epilogue: normalize and store. lane holds O[q=lr][d=db*16+4g+r]
    float inv = 1.0f / lrun;
    float* op = out + (size_t)qrow * ROWSTR + bh * DDIM;
#pragma unroll
    for (int db = 0; db < 8; ++db) {
        f32x4 o;
#pragma unroll
        for (int r = 0; r < 4; ++r) o[r] = acc[db][r] * inv;
        *(f32x4*)(op + db * 16 + g * 4) = o;
    }
}

extern "C" void kernel_launch(void* const* d_in, const int* in_sizes, int n_in,
                              void* d_out, int out_size, void* d_ws, size_t ws_size,
                              hipStream_t stream) {
    const float* q = (const float*)d_in[0];
    const float* k = (const float*)d_in[1];
    const float* v = (const float*)d_in[2];
    float* o = (float*)d_out;
    dim3 grid(32 * NQT);   // (b*H) * q-tiles
    dim3 block(256);
    fattn_kernel<<<grid, block, 0, stream>>>(q, k, v, o);
}

// Round 2
// 92.696 us; speedup vs baseline: 3.3122x; 3.3122x over previous
//
#include <hip/hip_runtime.h>

// Fused causal attention, S=2048 B=2 H=16 D=128, sbhd, fp32 in/out, bf16 MFMA.
// Round 2: paired q-tiles (uniform 33 kv-tiles/block), KVBLK=64, register
// prefetch of next K/V tile, conflict-free LDS layouts, defer-max.

#define S_LEN   2048
#define DDIM    128
#define ROWSTR  4096          // B*H*D element stride along s/t
#define QBLK    64
#define KVBLK   64
#define NQT     32            // S_LEN / QBLK
#define NF_INV  0.08838834764831845f   // 1/sqrt(128)

typedef __attribute__((ext_vector_type(4))) float f32x4;
typedef __attribute__((ext_vector_type(8))) short s16x8;
typedef __attribute__((ext_vector_type(4))) short s16x4;

__device__ inline short f2bf(float x) {
    union { float f; unsigned u; } v; v.f = x;
    unsigned r = v.u + 0x7fffu + ((v.u >> 16) & 1u);   // RNE
    return (short)(r >> 16);
}

__global__ __launch_bounds__(256, 2)
void fattn_kernel(const float* __restrict__ q, const float* __restrict__ k,
                  const float* __restrict__ v, float* __restrict__ out)
{
    // K: [64][128] bf16 rows, byte ^= (row&7)<<4  -> 16384 B
    // V: transposed chunks: chunk c=kv>>2 (16), addr = c*1032 + (dd ^ ((dd>>4)&7))*8
    __shared__ char ldsK[KVBLK * 256];
    __shared__ char ldsV[16 * 1032];

    const int tid = threadIdx.x;
    const int w   = tid >> 6;
    const int l   = tid & 63;
    const int g   = l >> 4;
    const int lr  = l & 15;

    const int bid = blockIdx.x;
    const int bh  = bid & 31;          // same-bh blocks land on same XCD (bid%8)
    const int pr  = bid >> 5;          // 0..15 pair index

    const float* qbh = q + bh * DDIM;
    const float* kbh = k + bh * DDIM;
    const float* vbh = v + bh * DDIM;

    // K staging map: row = krow0 + 16j, f32 cols kcolf..kcolf+7 (full-row b128 writes)
    const int krow0 = tid >> 4;
    const int kcolf = (tid & 15) * 8;
    // V staging map: d block vdb4*4.., kv chunks vkc and vkc+8
    const int vdb4  = tid & 31;
    const int vkc   = tid >> 5;

    f32x4 kreg[8], vreg[8];

    auto prefetch = [&](int kv0) {
        const float* kp = kbh + (size_t)(kv0 + krow0) * ROWSTR + kcolf;
#pragma unroll
        for (int j = 0; j < 4; ++j) {
            kreg[2 * j]     = *(const f32x4*)(kp + (size_t)16 * j * ROWSTR);
            kreg[2 * j + 1] = *(const f32x4*)(kp + (size_t)16 * j * ROWSTR + 4);
        }
        const float* vp = vbh + (size_t)(kv0 + vkc * 4) * ROWSTR + vdb4 * 4;
#pragma unroll
        for (int r = 0; r < 4; ++r) {
            vreg[r]     = *(const f32x4*)(vp + (size_t)r * ROWSTR);
            vreg[4 + r] = *(const f32x4*)(vp + (size_t)(32 + r) * ROWSTR);
        }
    };

    auto stage = [&]() {
        // K: 4 b128 writes, swizzled; (krow0+16j)&7 == krow0&7
        unsigned ksw = (unsigned)(krow0 & 7) << 4;
#pragma unroll
        for (int j = 0; j < 4; ++j) {
            s16x8 t;
#pragma unroll
            for (int i = 0; i < 4; ++i) {
                t[i]     = f2bf(kreg[2 * j][i]);
                t[4 + i] = f2bf(kreg[2 * j + 1][i]);
            }
            unsigned a = (unsigned)((krow0 + 16 * j) * 256 + kcolf * 2);
            *(s16x8*)(ldsK + (a ^ ksw)) = t;
        }
        // V: 8 b64 writes to transposed chunk layout
#pragma unroll
        for (int h = 0; h < 2; ++h) {
            int c = vkc + 8 * h;
#pragma unroll
            for (int jj = 0; jj < 4; ++jj) {
                int dd = vdb4 * 4 + jj;
                s16x4 t;
#pragma unroll
                for (int r = 0; r < 4; ++r) t[r] = f2bf(vreg[h * 4 + r][jj]);
                int dds = dd ^ ((dd >> 4) & 7);
                *(s16x4*)(ldsV + c * 1032 + dds * 8) = t;
            }
        }
    };

    prefetch(0);

    const int qts[2] = { pr, NQT - 1 - pr };

    for (int ph = 0; ph < 2; ++ph) {
        const int qt = qts[ph];
        const int nt = qt + 1;
        const int qb = qt * QBLK;
        const int qrow = qb + 16 * w + lr;

        // Q fragments (B-operand), pre-scaled
        s16x8 qf[4];
#pragma unroll
        for (int kk = 0; kk < 4; ++kk) {
            const float* qp = qbh + (size_t)qrow * ROWSTR + kk * 32 + g * 8;
            f32x4 a  = *(const f32x4*)qp;
            f32x4 b2 = *(const f32x4*)(qp + 4);
            s16x8 t;
#pragma unroll
            for (int i = 0; i < 4; ++i) {
                t[i]     = f2bf(a[i]  * NF_INV);
                t[4 + i] = f2bf(b2[i] * NF_INV);
            }
            qf[kk] = t;
        }

        f32x4 acc[8];
#pragma unroll
        for (int i = 0; i < 8; ++i) acc[i] = (f32x4){0.f, 0.f, 0.f, 0.f};
        float mrun = -INFINITY;
        float lrun = 0.0f;

        for (int t = 0; t < nt; ++t) {
            __syncthreads();            // previous tile's compute done
            stage();
            __syncthreads();            // LDS ready

            if (t + 1 < nt)      prefetch((t + 1) * KVBLK);
            else if (ph == 0)    prefetch(0);   // first tile of phase B

            const int kv0 = t * KVBLK;

            // ---- S^T = K · Q^T  (4 row-blocks x 4 k-chunks)
            f32x4 sa[4];
#pragma unroll
            for (int m = 0; m < 4; ++m) sa[m] = (f32x4){0.f, 0.f, 0.f, 0.f};
            unsigned rsw = (unsigned)(lr & 7) << 4;
#pragma unroll
            for (int m = 0; m < 4; ++m) {
                int row = 16 * m + lr;
#pragma unroll
                for (int kk = 0; kk < 4; ++kk) {
                    unsigned a = (unsigned)(row * 256 + kk * 64 + g * 16);
                    s16x8 kf = *(const s16x8*)(ldsK + (a ^ rsw));
                    sa[m] = __builtin_amdgcn_mfma_f32_16x16x32_bf16(kf, qf[kk], sa[m], 0, 0, 0);
                }
            }

            // ---- online softmax (row q=lr over lanes {lr, lr+16, lr+32, lr+48})
            float s_[16];
#pragma unroll
            for (int m = 0; m < 4; ++m)
#pragma unroll
                for (int r = 0; r < 4; ++r) s_[4 * m + r] = sa[m][r];

            if (t == nt - 1) {          // diagonal tile only
#pragma unroll
                for (int m = 0; m < 4; ++m)
#pragma unroll
                    for (int r = 0; r < 4; ++r) {
                        int kva = kv0 + 16 * m + 4 * g + r;
                        if (kva > qrow) s_[4 * m + r] = -INFINITY;
                    }
            }

            float mx = s_[0];
#pragma unroll
            for (int j = 1; j < 16; ++j) mx = fmaxf(mx, s_[j]);
            mx = fmaxf(mx, __shfl_xor(mx, 16));
            mx = fmaxf(mx, __shfl_xor(mx, 32));

            if (!__all(mx - mrun <= 8.0f)) {    // defer-max rescale
                float mnew = fmaxf(mrun, mx);
                float corr = __expf(mrun - mnew);
                lrun *= corr;
#pragma unroll
                for (int db = 0; db < 8; ++db)
#pragma unroll
                    for (int r = 0; r < 4; ++r) acc[db][r] *= corr;
                mrun = mnew;
            }

            float ts = 0.f;
#pragma unroll
            for (int j = 0; j < 16; ++j) {
                float p = __expf(s_[j] - mrun);
                s_[j] = p;
                ts += p;
            }
            ts += __shfl_xor(ts, 16);
            ts += __shfl_xor(ts, 32);
            lrun += ts;

            s16x8 pa0, pa1;
#pragma unroll
            for (int j = 0; j < 8; ++j) { pa0[j] = f2bf(s_[j]); pa1[j] = f2bf(s_[8 + j]); }

            // ---- O^T += V^T · P^T
#pragma unroll
            for (int db = 0; db < 8; ++db) {
                int dd  = db * 16 + lr;
                int dds = dd ^ (db & 7);
                const char* vb = ldsV + dds * 8;
                s16x4 v00 = *(const s16x4*)(vb + (g)      * 1032);
                s16x4 v01 = *(const s16x4*)(vb + (g + 4)  * 1032);
                s16x4 v10 = *(const s16x4*)(vb + (g + 8)  * 1032);
                s16x4 v11 = *(const s16x4*)(vb + (g + 12) * 1032);
                s16x8 vf0, vf1;
#pragma unroll
                for (int i = 0; i < 4; ++i) {
                    vf0[i] = v00[i]; vf0[4 + i] = v01[i];
                    vf1[i] = v10[i]; vf1[4 + i] = v11[i];
                }
                acc[db] = __builtin_amdgcn_mfma_f32_16x16x32_bf16(vf0, pa0, acc[db], 0, 0, 0);
                acc[db] = __builtin_amdgcn_mfma_f32_16x16x32_bf16(vf1, pa1, acc[db], 0, 0, 0);
            }
        }

        // ---- epilogue: lane holds O[q=qrow][d = db*16 + 4g + r]
        float inv = 1.0f / lrun;
        float* op = out + (size_t)qrow * ROWSTR + bh * DDIM;
#pragma unroll
        for (int db = 0; db < 8; ++db) {
            f32x4 o;
#pragma unroll
            for (int r = 0; r < 4; ++r) o[r] = acc[db][r] * inv;
            *(f32x4*)(op + db * 16 + g * 4) = o;
        }
    }
}

extern "C" void kernel_launch(void* const* d_in, const int* in_sizes, int n_in,
                              void* d_out, int out_size, void* d_ws, size_t ws_size,
                              hipStream_t stream) {
    const float* q = (const float*)d_in[0];
    const float* k = (const float*)d_in[1];
    const float* v = (const float*)d_in[2];
    float* o = (float*)d_out;
    dim3 grid(32 * 16);   // bh-major: same head's 16 pair-blocks share an XCD
    dim3 block(256);
    fattn_kernel<<<grid, block, 0, stream>>>(q, k, v, o);
}

// Round 3
// 89.581 us; speedup vs baseline: 3.4274x; 1.0348x over previous
//
#include <hip/hip_runtime.h>
#include <hip/hip_bf16.h>

// Fused causal attention, S=2048 B=2 H=16 D=128, sbhd, fp32 in/out, bf16 MFMA.
// Round 3: double-buffered LDS (1 barrier/tile), packed cvt_pk bf16 conversion,
// b128 V fragments via kv-permuted Vt layout, exp2-domain softmax.

#define DDIM    128
#define ROWSTR  4096          // B*H*D element stride along s/t
#define QBLK    64
#define KVBLK   64
#define NQT     32            // S_LEN / QBLK
#define QSCALE  0.1275174190023967f   // (1/sqrt(128)) * log2(e)

typedef __attribute__((ext_vector_type(4))) float f32x4;
typedef __attribute__((ext_vector_type(8))) short s16x8;
typedef __attribute__((ext_vector_type(4))) short s16x4;

__device__ inline unsigned pk2bf(float a, float b) {
    union { __hip_bfloat162 h; unsigned u; } cv;
    cv.h = __float22bfloat162_rn(float2{a, b});
    return cv.u;
}

__global__ __launch_bounds__(256, 2)
void fattn_kernel(const float* __restrict__ q, const float* __restrict__ k,
                  const float* __restrict__ v, float* __restrict__ out)
{
    // K: [64 rows][128 bf16], row-XOR swizzle (byte ^= (row&7)<<4), 16 KB/buf
    // V: Vt[dd 0..127][64 kv bf16] pitch 128 B, kv permuted pos=32h+8cc+4u+r,
    //    slot bits (byte 4..6) XOR'd with sw(dd)=(dd+(dd>>3))&7, 16 KB/buf
    __shared__ char ldsK[2][KVBLK * 256];
    __shared__ char ldsV[2][DDIM * 128];

    const int tid = threadIdx.x;
    const int w = tid >> 6, l = tid & 63, g = l >> 4, lr = l & 15;
    const int bid = blockIdx.x;
    const int bh = bid & 31;        // same-head blocks share an XCD (bid%8)
    const int pr = bid >> 5;        // pair index 0..15

    const float* qbh = q + bh * DDIM;
    const float* kbh = k + bh * DDIM;
    const float* vbh = v + bh * DDIM;

    // staging maps
    const int krow0 = tid >> 4;            // 0..15, rows krow0+16j
    const int kcolf = (tid & 15) * 8;      // f32 col base
    const int vdb4  = tid & 31;            // d block of 4
    const int vkc   = tid >> 5;            // kv chunk of 4 (0..7)
    const int vu    = (vkc >> 2) & 1, vcc = vkc & 3;

    f32x4 kreg[8], vreg[8];

    auto prefetch = [&](int kv0) {
        const float* kp = kbh + (size_t)(kv0 + krow0) * ROWSTR + kcolf;
#pragma unroll
        for (int j = 0; j < 4; ++j) {
            kreg[2 * j]     = *(const f32x4*)(kp + (size_t)16 * j * ROWSTR);
            kreg[2 * j + 1] = *(const f32x4*)(kp + (size_t)16 * j * ROWSTR + 4);
        }
        const float* vp = vbh + (size_t)(kv0 + vkc * 4) * ROWSTR + vdb4 * 4;
#pragma unroll
        for (int r = 0; r < 4; ++r) {
            vreg[r]     = *(const f32x4*)(vp + (size_t)r * ROWSTR);
            vreg[4 + r] = *(const f32x4*)(vp + (size_t)(32 + r) * ROWSTR);
        }
    };

    auto stage = [&](char* bk, char* bv) {
        unsigned ksw = (unsigned)(krow0 & 7) << 4;
#pragma unroll
        for (int j = 0; j < 4; ++j) {
            s16x8 t;
            unsigned* tu = (unsigned*)&t;
            tu[0] = pk2bf(kreg[2 * j][0],     kreg[2 * j][1]);
            tu[1] = pk2bf(kreg[2 * j][2],     kreg[2 * j][3]);
            tu[2] = pk2bf(kreg[2 * j + 1][0], kreg[2 * j + 1][1]);
            tu[3] = pk2bf(kreg[2 * j + 1][2], kreg[2 * j + 1][3]);
            unsigned a = (unsigned)((krow0 + 16 * j) * 256 + kcolf * 2);
            *(s16x8*)(bk + (a ^ ksw)) = t;
        }
#pragma unroll
        for (int h = 0; h < 2; ++h)
#pragma unroll
            for (int jj = 0; jj < 4; ++jj) {
                int dd = vdb4 * 4 + jj;
                int sw = (dd + (dd >> 3)) & 7;
                int slot = 4 * h + vcc;
                unsigned a = (unsigned)(dd * 128 + (((slot ^ sw)) << 4) + 8 * vu);
                s16x4 t;
                unsigned* tu = (unsigned*)&t;
                tu[0] = pk2bf(vreg[4 * h + 0][jj], vreg[4 * h + 1][jj]);
                tu[1] = pk2bf(vreg[4 * h + 2][jj], vreg[4 * h + 3][jj]);
                *(s16x4*)(bv + a) = t;
            }
    };

    s16x8 qf[4];
    auto load_qf = [&](int qrow) {
#pragma unroll
        for (int kk = 0; kk < 4; ++kk) {
            const float* qp = qbh + (size_t)qrow * ROWSTR + kk * 32 + g * 8;
            f32x4 a  = *(const f32x4*)qp;
            f32x4 b2 = *(const f32x4*)(qp + 4);
            unsigned* tu = (unsigned*)&qf[kk];
            tu[0] = pk2bf(a[0]  * QSCALE, a[1]  * QSCALE);
            tu[1] = pk2bf(a[2]  * QSCALE, a[3]  * QSCALE);
            tu[2] = pk2bf(b2[0] * QSCALE, b2[1] * QSCALE);
            tu[3] = pk2bf(b2[2] * QSCALE, b2[3] * QSCALE);
        }
    };

    const int ntA = pr + 1;
    const int ntB = NQT - pr;
    const int total = ntA + ntB;        // uniform 33
    const int qtB = NQT - 1 - pr;

    int qrow = pr * QBLK + 16 * w + lr;
    load_qf(qrow);

    f32x4 acc[8];
#pragma unroll
    for (int i = 0; i < 8; ++i) acc[i] = (f32x4){0.f, 0.f, 0.f, 0.f};
    float mrun = -INFINITY, lrun = 0.f;

    auto kv_of = [&](int tt) { return (tt < ntA ? tt : tt - ntA) * KVBLK; };

    // prologue: tile 0 staged, tile 1 in regs
    prefetch(0);
    stage(ldsK[0], ldsV[0]);
    prefetch(kv_of(1));
    __syncthreads();

    for (int tt = 0; tt < total; ++tt) {
        const int cur = tt & 1;
        const bool phB = tt >= ntA;
        const int t  = phB ? tt - ntA : tt;
        const int nt = phB ? ntB : ntA;

        if (tt + 1 < total) {
            stage(ldsK[cur ^ 1], ldsV[cur ^ 1]);       // tile tt+1 (regs ready)
            if (tt + 2 < total) prefetch(kv_of(tt + 2));
        }

        const int kv0 = t * KVBLK;
        const char* bk = ldsK[cur];
        const char* bv = ldsV[cur];

        // ---- S^T = K · Q^T (4 row-blocks × 4 k-chunks)
        f32x4 sa[4];
#pragma unroll
        for (int m = 0; m < 4; ++m) sa[m] = (f32x4){0.f, 0.f, 0.f, 0.f};
        unsigned rsw = (unsigned)(lr & 7) << 4;
#pragma unroll
        for (int m = 0; m < 4; ++m) {
            int row = 16 * m + lr;
#pragma unroll
            for (int kk = 0; kk < 4; ++kk) {
                unsigned a = (unsigned)(row * 256 + kk * 64 + g * 16);
                s16x8 kf = *(const s16x8*)(bk + (a ^ rsw));
                sa[m] = __builtin_amdgcn_mfma_f32_16x16x32_bf16(kf, qf[kk], sa[m], 0, 0, 0);
            }
        }

        // ---- online softmax (exp2 domain; row q=lr over lanes {lr,+16,+32,+48})
        float s_[16];
#pragma unroll
        for (int m = 0; m < 4; ++m)
#pragma unroll
            for (int r = 0; r < 4; ++r) s_[4 * m + r] = sa[m][r];

        if (t == nt - 1) {                 // diagonal tile
#pragma unroll
            for (int m = 0; m < 4; ++m)
#pragma unroll
                for (int r = 0; r < 4; ++r) {
                    int kva = kv0 + 16 * m + 4 * g + r;
                    if (kva > qrow) s_[4 * m + r] = -INFINITY;
                }
        }

        float mx = s_[0];
#pragma unroll
        for (int j = 1; j < 16; ++j) mx = fmaxf(mx, s_[j]);
        mx = fmaxf(mx, __shfl_xor(mx, 16));
        mx = fmaxf(mx, __shfl_xor(mx, 32));

        if (!__all(mx - mrun <= 8.0f)) {   // defer-max rescale (2^8 headroom)
            float mnew = fmaxf(mrun, mx);
            float corr = __builtin_amdgcn_exp2f(mrun - mnew);
            lrun *= corr;
#pragma unroll
            for (int db = 0; db < 8; ++db)
#pragma unroll
                for (int r = 0; r < 4; ++r) acc[db][r] *= corr;
            mrun = mnew;
        }

        float ts = 0.f;
#pragma unroll
        for (int j = 0; j < 16; ++j) {
            float p = __builtin_amdgcn_exp2f(s_[j] - mrun);
            s_[j] = p;
            ts += p;
        }
        ts += __shfl_xor(ts, 16);
        ts += __shfl_xor(ts, 32);
        lrun += ts;

        s16x8 pa0, pa1;
        {
            unsigned* p0 = (unsigned*)&pa0;
            unsigned* p1 = (unsigned*)&pa1;
#pragma unroll
            for (int j = 0; j < 4; ++j) {
                p0[j] = pk2bf(s_[2 * j],     s_[2 * j + 1]);
                p1[j] = pk2bf(s_[8 + 2 * j], s_[8 + 2 * j + 1]);
            }
        }

        // ---- O^T += V^T · P^T : one b128 per fragment
#pragma unroll
        for (int db = 0; db < 8; ++db) {
            int dd = db * 16 + lr;
            int sw = (dd + (dd >> 3)) & 7;
            const char* vb = bv + dd * 128;
            s16x8 vf0 = *(const s16x8*)(vb + (((g)     ^ sw) << 4));
            s16x8 vf1 = *(const s16x8*)(vb + (((4 + g) ^ sw) << 4));
            acc[db] = __builtin_amdgcn_mfma_f32_16x16x32_bf16(vf0, pa0, acc[db], 0, 0, 0);
            acc[db] = __builtin_amdgcn_mfma_f32_16x16x32_bf16(vf1, pa1, acc[db], 0, 0, 0);
        }

        if (t == nt - 1) {
            // ---- epilogue: lane holds O[qrow][d = db*16 + 4g + r]
            float inv = 1.0f / lrun;
            float* op = out + (size_t)qrow * ROWSTR + bh * DDIM;
#pragma unroll
            for (int db = 0; db < 8; ++db) {
                f32x4 o;
#pragma unroll
                for (int r = 0; r < 4; ++r) o[r] = acc[db][r] * inv;
                *(f32x4*)(op + db * 16 + g * 4) = o;
            }
            if (!phB) {                     // reset context for phase B
#pragma unroll
                for (int i = 0; i < 8; ++i) acc[i] = (f32x4){0.f, 0.f, 0.f, 0.f};
                mrun = -INFINITY; lrun = 0.f;
                qrow = qtB * QBLK + 16 * w + lr;
                load_qf(qrow);
            }
        }
        __syncthreads();
    }
}

extern "C" void kernel_launch(void* const* d_in, const int* in_sizes, int n_in,
                              void* d_out, int out_size, void* d_ws, size_t ws_size,
                              hipStream_t stream) {
    const float* q = (const float*)d_in[0];
    const float* k = (const float*)d_in[1];
    const float* v = (const float*)d_in[2];
    float* o = (float*)d_out;
    dim3 grid(32 * 16);   // bh-major: a head's 16 pair-blocks share an XCD
    dim3 block(256);
    fattn_kernel<<<grid, block, 0, stream>>>(q, k, v, o);
}